// Round 9
// baseline (179.383 us; speedup 1.0000x reference)
//
#include <hip/hip_runtime.h>

// B=4, S=4096, D_IN=1024, D_QK=D_V=64
// out = softmax(relu(XWq+bq) @ relu(XWk+bk)^T) @ relu(XWv+bv) * mask

typedef short s16x8 __attribute__((ext_vector_type(8)));      // 8x16b (4 VGPRs) MFMA frag
typedef _Float16 f16x8 __attribute__((ext_vector_type(8)));   // 8 fp16 (4 VGPRs)
typedef float fx4   __attribute__((ext_vector_type(4)));      // MFMA accum frag
typedef unsigned short u16x4 __attribute__((ext_vector_type(4)));

#define LOG2E 1.4426950408889634f

__device__ __forceinline__ unsigned short f2bf(float x) {   // fp32 -> bf16 RTN
    unsigned int u = __float_as_uint(x);
    u += 0x7FFFu + ((u >> 16) & 1u);
    return (unsigned short)(u >> 16);
}
__device__ __forceinline__ float bf2f(unsigned short b) {
    return __uint_as_float(((unsigned int)b) << 16);
}

// ---------------------------------------------------------------------------
// Kernel 1 (merged): blocks 0..47: W^T fp16 prep. blocks 48..1071: X -> fp16
// TILED XT[tile 256][kc 16][row 64][kk 64]. X is read in FULL 4 KB rows (one
// row per wave, perfectly sequential -> all HBM channels), never in strided
// column-chunks. XT tiles are contiguous 8 KB chunks, so proj's reads are
// sequential too. This kills the 4 KB-stride geometry shared by all previous
// proj variants (the suspected channel-aliasing behind the invariant ~49 us).
// ---------------------------------------------------------------------------
__global__ __launch_bounds__(256) void prep_kernel(
    const float* __restrict__ X,
    const float* __restrict__ Wq, const float* __restrict__ Wk, const float* __restrict__ Wv,
    _Float16* __restrict__ wt_h, _Float16* __restrict__ xt)
{
    __shared__ __align__(16) _Float16 sh[64][72];   // W branch only
    const int bid = blockIdx.x;
    const int t   = threadIdx.x;

    if (bid < 48) {
        // ---- W^T fp16: W[1024][64] -> wt_h[3][64][1024] ----
        const int y  = bid >> 4;
        const int kt = bid & 15;
        const float* W = (y == 0) ? Wq : (y == 1) ? Wk : Wv;

        const int kl = t >> 2;
        const int c0 = (t & 3) * 16;
        const float* src = W + (size_t)(kt * 64 + kl) * 64 + c0;
        #pragma unroll
        for (int j = 0; j < 4; j++) {
            fx4 v = *(const fx4*)(src + j * 4);
            #pragma unroll
            for (int i = 0; i < 4; i++)
                sh[c0 + j * 4 + i][kl] = (_Float16)v[i];
        }
        __syncthreads();

        const int c  = t >> 2;
        const int k0 = (t & 3) * 16;
        size_t o = (size_t)(y * 64 + c) * 1024 + kt * 64 + k0;
        *(f16x8*)(wt_h + o)     = *(const f16x8*)&sh[c][k0];
        *(f16x8*)(wt_h + o + 8) = *(const f16x8*)&sh[c][k0 + 8];
    } else {
        // ---- X fp32 -> XT fp16 tiled ----
        const int xb   = bid - 48;        // 0..1023
        const int tile = xb >> 2;         // 0..255 (64-row m-tile)
        const int qrt  = xb & 3;          // quarter: 16 rows
        const int rl   = t >> 6;          // 0..3
        const int c    = (t & 63) * 16;   // col 0..1008
        const int kc   = c >> 6;          // 0..15
        const int kk   = c & 63;          // 0/16/32/48

        #pragma unroll
        for (int it = 0; it < 4; it++) {
            int row = qrt * 16 + it * 4 + rl;
            const float* src = X + (((size_t)(tile * 64 + row)) << 10) + c;
            _Float16 h[16];
            #pragma unroll
            for (int j = 0; j < 4; j++) {
                fx4 v = *(const fx4*)(src + j * 4);
                #pragma unroll
                for (int i = 0; i < 4; i++)
                    h[j * 4 + i] = (_Float16)v[i];
            }
            _Float16* dst = xt + ((((size_t)tile * 16 + kc) * 64 + row) << 6) + kk;
            *(f16x8*)dst       = *(const f16x8*)&h[0];
            *(f16x8*)(dst + 8) = *(const f16x8*)&h[8];
        }
    }
}

// ---------------------------------------------------------------------------
// Kernel 2: projection v5 — fp16 MFMA, zero K-loop VALU. A-fragments load
// DIRECTLY from tiled XT (16 B/lane, contiguous 8 KB per (tile,kc)); W^T fp16
// staged in LDS K-chunks of 256 (33.8 KB). XCD swizzle keeps the 3 y-blocks
// of an m-tile on one XCD (XT L2 reuse). grid 768, 4 blocks/CU possible.
// y==0 -> q hi/lo bf16; y==1 -> k bf16; y==2 -> V^T TILED [b][stile][d][ss].
// ---------------------------------------------------------------------------
__global__ __launch_bounds__(256, 4) void proj_kernel(
    const _Float16* __restrict__ xt, const _Float16* __restrict__ wt_h,
    const float* __restrict__ bq, const float* __restrict__ bk, const float* __restrict__ bv,
    unsigned short* __restrict__ q_hi, unsigned short* __restrict__ q_lo,
    unsigned short* __restrict__ k_bf, unsigned short* __restrict__ vt_g)
{
    __shared__ __align__(16) _Float16 wls[64][264];  // [col][k0..255, +8 pad]

    const int tid  = threadIdx.x;
    const int lane = tid & 63;
    const int w    = tid >> 6;      // 0..3 (16-row strip per wave)
    const int quad = lane >> 4;
    const int l15  = lane & 15;

    // XCD swizzle decode: f = (mt & 7) + 8*(y + 3*(mt >> 3))
    const int f   = blockIdx.x;
    const int xcd = f & 7;
    const int jj  = f >> 3;
    const int y   = jj % 3;         // 0=q 1=k 2=v
    const int mt  = (jj / 3) * 8 + xcd;
    const int m0  = mt * 64;

    // A-fragment base in tiled XT: [mt][kc][row][kk]
    const _Float16* xtb = xt + (((size_t)mt * 16) * 64 + (w * 16 + l15)) * 64 + quad * 8;
    // frag(kc, ks) at xtb + kc*4096 + ks*32

    // W chunk staging: 64 cols x 256 k per chunk
    const int wcol = tid >> 2;            // 0..63
    const int wk0  = (tid & 3) * 64;      // 0/64/128/192
    const size_t wgb = (size_t)(y * 64 + wcol) * 1024 + wk0;

    f16x8 wr[8];
    #pragma unroll
    for (int i = 0; i < 8; i++)
        wr[i] = *(const f16x8*)(wt_h + wgb + i * 8);

    // prefetch A-fragments for kc=0
    f16x8 xc0 = *(const f16x8*)(xtb);
    f16x8 xc1 = *(const f16x8*)(xtb + 32);

    fx4 acc[4];
    #pragma unroll
    for (int nt = 0; nt < 4; nt++) acc[nt] = (fx4){0.f, 0.f, 0.f, 0.f};

    for (int ch = 0; ch < 4; ch++) {      // 4 chunks x 256 K
        if (ch) __syncthreads();          // prev chunk's LDS readers done
        #pragma unroll
        for (int i = 0; i < 8; i++)
            *(f16x8*)&wls[wcol][wk0 + i * 8] = wr[i];
        __syncthreads();
        if (ch < 3) {                     // prefetch next W chunk (L2-hit)
            #pragma unroll
            for (int i = 0; i < 8; i++)
                wr[i] = *(const f16x8*)(wt_h + wgb + (ch + 1) * 256 + i * 8);
        }

        #pragma unroll
        for (int kk = 0; kk < 4; kk++) {
            const int kc = ch * 4 + kk;
            // prefetch next kc's A-fragments while computing this one
            f16x8 xn0, xn1;
            if (kc < 15) {
                xn0 = *(const f16x8*)(xtb + (kc + 1) * 4096);
                xn1 = *(const f16x8*)(xtb + (kc + 1) * 4096 + 32);
            }
            #pragma unroll
            for (int nt = 0; nt < 4; nt++) {
                const int ko = kk * 64 + quad * 8;
                f16x8 b0 = *(const f16x8*)&wls[nt * 16 + l15][ko];
                f16x8 b1 = *(const f16x8*)&wls[nt * 16 + l15][ko + 32];
                acc[nt] = __builtin_amdgcn_mfma_f32_16x16x32_f16(xc0, b0, acc[nt], 0, 0, 0);
                acc[nt] = __builtin_amdgcn_mfma_f32_16x16x32_f16(xc1, b1, acc[nt], 0, 0, 0);
            }
            xc0 = xn0; xc1 = xn1;
        }
    }
    __syncthreads();   // all LDS reads done before vtr alias writes

    // epilogue: bias + relu, write per-matrix
    const float* bias = (y == 0) ? bq : (y == 1) ? bk : bv;

    unsigned short* vtr = (unsigned short*)&wls[0][0];  // alias: [64 d][72]

    #pragma unroll
    for (int nt = 0; nt < 4; nt++) {
        int col = nt * 16 + l15;
        float bb = bias[col];
        int rloc = w * 16 + quad * 4;   // local row 0..63
        #pragma unroll
        for (int r = 0; r < 4; r++) {
            float v = acc[nt][r] + bb;
            v = fmaxf(v, 0.f);
            size_t grow = (size_t)(m0 + rloc + r);
            if (y == 0) {
                unsigned short h = f2bf(v);
                unsigned short l = f2bf(v - bf2f(h));
                q_hi[grow * 64 + col] = h;
                q_lo[grow * 64 + col] = l;
            } else if (y == 1) {
                k_bf[grow * 64 + col] = f2bf(v);
            } else {
                vtr[col * 72 + rloc + r] = f2bf(v);  // transpose via LDS
            }
        }
    }
    if (y == 2) {
        __syncthreads();
        // tiled V^T write: vt_g[mt][d][ss], contiguous 8 KB per tile
        int rowd = tid >> 2;          // d 0..63
        int off  = (tid & 3) * 16;    // ss chunk (16 el = 32 B)
        s16x8 v0 = *(const s16x8*)&vtr[rowd * 72 + off];
        s16x8 v1 = *(const s16x8*)&vtr[rowd * 72 + off + 8];
        unsigned short* dst = vt_g + ((size_t)mt * 64 + rowd) * 64 + off;
        *(s16x8*)(dst)     = v0;
        *(s16x8*)(dst + 8) = v1;
    }
}

// ---------------------------------------------------------------------------
// Kernel 3: fused attention, KV-split. grid (64 qtiles, 8 chunks, 4 batch) =
// 2048 blocks. Block = 64 q-rows, 4 waves, 8 KV tiles each. LDS 23.5 KB ->
// 6 blocks/CU. KV register-prefetch of tile it+1 during compute. V^T now in
// TILED layout [b*64+it][d][ss]: reads are contiguous 8 KB per tile (was
// 64 rows x 128 B at 8 KB stride). Writes UNNORMALIZED partial O (bf16) and
// row-sum l (fp32). No online max: q,k >= 0 post-relu => exp safe in fp32.
// ---------------------------------------------------------------------------
__global__ __launch_bounds__(256, 6) void attn_kernel(
    const unsigned short* __restrict__ q_hi, const unsigned short* __restrict__ q_lo,
    const unsigned short* __restrict__ k_bf, const unsigned short* __restrict__ vt_g,
    unsigned short* __restrict__ pOb, float* __restrict__ pL)
{
    __shared__ __align__(16) unsigned short kt[64][72];      // [key][dim]
    __shared__ __align__(16) unsigned short vt[64][72];      // [dim][key]  (V^T)
    __shared__ __align__(16) unsigned short pt[4][16][40];   // per-wave P [q][key half]

    const int tid  = threadIdx.x;
    const int lane = tid & 63;
    const int w    = tid >> 6;
    const int quad = lane >> 4;
    const int l15  = lane & 15;
    const int ck   = blockIdx.y;         // key chunk (512 keys)
    const int b    = blockIdx.z;
    const int q0   = blockIdx.x * 64;    // within batch

    // Q fragments (A layout: m=lane&15, k=quad*8+j), split hi/lo
    const size_t qoff = ((size_t)b * 4096 + q0 + w * 16 + l15) * 64 + quad * 8;
    s16x8 qh0 = *(const s16x8*)(q_hi + qoff);
    s16x8 qh1 = *(const s16x8*)(q_hi + qoff + 32);
    s16x8 ql0 = *(const s16x8*)(q_lo + qoff);
    s16x8 ql1 = *(const s16x8*)(q_lo + qoff + 32);

    fx4 accO[4];
    #pragma unroll
    for (int nt = 0; nt < 4; nt++) accO[nt] = (fx4){0.f, 0.f, 0.f, 0.f};
    float lsum[4] = {0.f, 0.f, 0.f, 0.f};

    const unsigned short* kgb = k_bf + (size_t)b * 4096 * 64;  // [s][64]
    const unsigned short* vgb = vt_g + (size_t)b * 64 * 4096;  // tiled [it][d][ss]

    const int srow = tid >> 3;        // 0..31
    const int soff = (tid & 7) * 8;

    // prefetch KV tile 0 into registers
    s16x8 kr[2], vr[2];
    {
        const int it0 = ck * 8;
        const unsigned short* kg = kgb + (size_t)it0 * 4096;
        const unsigned short* vg = vgb + (size_t)it0 * 4096;
        #pragma unroll
        for (int i = 0; i < 2; i++) {
            int row = srow + i * 32;
            kr[i] = *(const s16x8*)(kg + (size_t)row * 64 + soff);
            vr[i] = *(const s16x8*)(vg + (size_t)row * 64 + soff);
        }
    }

    for (int i2 = 0; i2 < 8; i2++) {
        const int it = ck * 8 + i2;
        if (i2) __syncthreads();         // prev iter's LDS readers done
        #pragma unroll
        for (int i = 0; i < 2; i++) {
            int row = srow + i * 32;
            *(s16x8*)&kt[row][soff] = kr[i];
            *(s16x8*)&vt[row][soff] = vr[i];
        }
        __syncthreads();
        if (i2 < 7) {                    // prefetch next tile during compute
            const unsigned short* kg = kgb + (size_t)(it + 1) * 4096;
            const unsigned short* vg = vgb + (size_t)(it + 1) * 4096;
            #pragma unroll
            for (int i = 0; i < 2; i++) {
                int row = srow + i * 32;
                kr[i] = *(const s16x8*)(kg + (size_t)row * 64 + soff);
                vr[i] = *(const s16x8*)(vg + (size_t)row * 64 + soff);
            }
        }

        #pragma unroll
        for (int kh = 0; kh < 2; kh++) {
            // S = Q K^T for 32-key half (hi/lo compensated)
            #pragma unroll
            for (int nt2 = 0; nt2 < 2; nt2++) {
                int key = kh * 32 + nt2 * 16 + l15;
                s16x8 k0 = *(const s16x8*)&kt[key][quad * 8];
                s16x8 k1 = *(const s16x8*)&kt[key][32 + quad * 8];
                fx4 sc = (fx4){0.f, 0.f, 0.f, 0.f};
                sc = __builtin_amdgcn_mfma_f32_16x16x32_bf16(qh0, k0, sc, 0, 0, 0);
                sc = __builtin_amdgcn_mfma_f32_16x16x32_bf16(ql0, k0, sc, 0, 0, 0);
                sc = __builtin_amdgcn_mfma_f32_16x16x32_bf16(qh1, k1, sc, 0, 0, 0);
                sc = __builtin_amdgcn_mfma_f32_16x16x32_bf16(ql1, k1, sc, 0, 0, 0);
                // P = exp(S) -> bf16 -> wave-private LDS (C -> A layout)
                #pragma unroll
                for (int r = 0; r < 4; r++) {
                    float p = __builtin_amdgcn_exp2f(sc[r] * LOG2E);
                    unsigned short pb = f2bf(p);
                    lsum[r] += bf2f(pb);   // denominator matches rounded numerator
                    pt[w][quad * 4 + r][nt2 * 16 + l15] = pb;
                }
            }
            // O += P_half V_half  (k=32 exactly fills one MFMA)
            s16x8 pa = *(const s16x8*)&pt[w][l15][quad * 8];
            #pragma unroll
            for (int nt = 0; nt < 4; nt++) {
                s16x8 vf = *(const s16x8*)&vt[nt * 16 + l15][kh * 32 + quad * 8];
                accO[nt] = __builtin_amdgcn_mfma_f32_16x16x32_bf16(pa, vf, accO[nt], 0, 0, 0);
            }
        }
    }

    // reduce row-sums across the 16 lanes sharing each row group
    #pragma unroll
    for (int r = 0; r < 4; r++) {
        float v = lsum[r];
        #pragma unroll
        for (int o = 1; o < 16; o <<= 1) v += __shfl_xor(v, o);
        lsum[r] = v;
    }
    // write partials: pOb[ck][b*4096+q][64] (bf16), pL[ck][b*4096+q] (fp32)
    #pragma unroll
    for (int r = 0; r < 4; r++) {
        int qrow = q0 + w * 16 + quad * 4 + r;
        size_t grow = (size_t)b * 4096 + qrow;
        #pragma unroll
        for (int nt = 0; nt < 4; nt++)
            pOb[((size_t)ck * 16384 + grow) * 64 + nt * 16 + l15] = f2bf(accO[nt][r]);
        if (l15 == 0)
            pL[(size_t)ck * 16384 + grow] = lsum[r];
    }
}

// ---------------------------------------------------------------------------
// Kernel 4: combine partials: out = (sum_c pOb) * mask / (sum_c pL)
// ---------------------------------------------------------------------------
__global__ __launch_bounds__(256) void combine_kernel(
    const unsigned short* __restrict__ pOb, const float* __restrict__ pL,
    const float* __restrict__ mask, float* __restrict__ out)
{
    int idx = blockIdx.x * 256 + threadIdx.x;   // 262144 = (b*4096+s)*16 + dgrp
    int q  = idx >> 4;
    int dg = idx & 15;
    fx4 s = (fx4){0.f, 0.f, 0.f, 0.f};
    float l = 0.f;
    #pragma unroll
    for (int c = 0; c < 8; c++) {
        u16x4 h = *(const u16x4*)(pOb + ((size_t)c * 16384 + q) * 64 + dg * 4);
        s.x += bf2f(h.x);
        s.y += bf2f(h.y);
        s.z += bf2f(h.z);
        s.w += bf2f(h.w);
        l += pL[(size_t)c * 16384 + q];
    }
    float scale = mask[q] / l;
    *(fx4*)(out + (size_t)q * 64 + dg * 4) = s * scale;
}

// ---------------------------------------------------------------------------
extern "C" void kernel_launch(void* const* d_in, const int* in_sizes, int n_in,
                              void* d_out, int out_size, void* d_ws, size_t ws_size,
                              hipStream_t stream)
{
    const float* X    = (const float*)d_in[0];
    const float* mask = (const float*)d_in[1];
    const float* Wq   = (const float*)d_in[2];
    const float* bq   = (const float*)d_in[3];
    const float* Wk   = (const float*)d_in[4];
    const float* bk   = (const float*)d_in[5];
    const float* Wv   = (const float*)d_in[6];
    const float* bv   = (const float*)d_in[7];
    float* out = (float*)d_out;

    char* ws = (char*)d_ws;
    unsigned short* q_hi  = (unsigned short*)(ws);                       // 2 MB
    unsigned short* q_lo  = (unsigned short*)(ws + (size_t)(2u << 20));  // 2 MB
    unsigned short* k_bf  = (unsigned short*)(ws + (size_t)(4u << 20));  // 2 MB
    unsigned short* vt_g  = (unsigned short*)(ws + (size_t)(6u << 20));  // 2 MB tiled [b*64+it][d][ss]
    _Float16*       wt_h  = (_Float16*)(ws + (size_t)(8u << 20));        // 384 KB fp16 W^T
    _Float16*       xt    = (_Float16*)(ws + (size_t)(9u << 20));        // 32 MB fp16 XT (tiled)
    // pOb ALIASES xt's first half: attn writes it only after proj finished
    // reading xt (stream-serialized), so no hazard.
    unsigned short* pOb   = (unsigned short*)(ws + (size_t)(9u << 20));  // 16 MB [8][16384][64] bf16
    float*          pL    = (float*)(ws + (size_t)(41u << 20));          // 512 KB [8][16384]

    hipLaunchKernelGGL(prep_kernel, dim3(1072), dim3(256), 0, stream,
                       X, Wq, Wk, Wv, wt_h, xt);
    hipLaunchKernelGGL(proj_kernel, dim3(768), dim3(256), 0, stream,
                       xt, wt_h, bq, bk, bv, q_hi, q_lo, k_bf, vt_g);
    hipLaunchKernelGGL(attn_kernel, dim3(64, 8, 4), dim3(256), 0, stream,
                       q_hi, q_lo, k_bf, vt_g, pOb, pL);
    hipLaunchKernelGGL(combine_kernel, dim3(1024), dim3(256), 0, stream,
                       pOb, pL, mask, out);
}